// Round 8
// baseline (445.499 us; speedup 1.0000x reference)
//
#include <hip/hip_runtime.h>
#include <hip/hip_bf16.h>
#include <float.h>

// Problem: B=128, D=64, H=W=32, K=512. N = 131072 rows.
#define NTOT 131072

// d_out element offsets (fp32, concatenated in return order)
#define OFF_LOSS  0
#define OFF_QUANT 1
#define OFF_PERP  8388609
#define OFF_OH    8388610

#define FLAG_BIT (1 << 16)
#define TAU      1.5e-3f

// ws int-word layout: [0] loss (f32 bits), [1] done, [2..513] counts,
// [640..17023] elo table (512x64 bf16 = 32768 shorts = 16384 words)
#define W_ELO 640

typedef __attribute__((ext_vector_type(8))) short short8;
typedef __attribute__((ext_vector_type(4))) short short4v;
typedef __attribute__((ext_vector_type(4))) float f32x4;

__device__ inline unsigned short f2bf(float f) {
    unsigned u = __builtin_bit_cast(unsigned, f);
    unsigned r = (u + 0x7fffu + ((u >> 16) & 1u)) >> 16;   // RNE
    return (unsigned short)r;
}
__device__ inline float bf2f(unsigned short h) {
    return __builtin_bit_cast(float, ((unsigned)h) << 16);
}

// prep: zero loss/done/counts; build bf16-lo codebook table in ws.
__global__ __launch_bounds__(512)
void vq_prep(const float* __restrict__ cb, int* __restrict__ wsi) {
    int tid = blockIdx.x * 512 + threadIdx.x;   // 0..1023
    if (tid < 514) wsi[tid] = 0;
    short* elo = (short*)(wsi + W_ELO);
    int row = tid >> 1, half = tid & 1;
    const float4* cb4 = (const float4*)cb;
#pragma unroll
    for (int j = 0; j < 8; ++j) {
        float4 v = cb4[(row << 4) + (half << 3) + j];
        float vv[4] = {v.x, v.y, v.z, v.w};
        short4v l4;
#pragma unroll
        for (int e = 0; e < 4; ++e) {
            unsigned short h = f2bf(vv[e]);
            l4[e] = (short)f2bf(vv[e] - bf2f(h));
        }
        *(short4v*)(elo + (row << 6) + (half << 5) + (j << 2)) = l4;
    }
}

// Main: 512 WGs x 512 thr, 2 WGs/CU (LDS ~72 KB). WG owns 256 rows
// (b = wg>>2, sp0 = (wg&3)*256). Wave w owns 32 rows (2 x-tiles).
// A-hi frags from LDS (swizzled), A-lo frags from global elo table (L2-hot).
__global__ __launch_bounds__(512, 4)
void vq_main(const float* __restrict__ x, const float* __restrict__ cb,
             int* __restrict__ wsi, float* __restrict__ out) {
    __shared__ short Ehi[512 * 64];   // 64 KB, bf16 hi, XOR-swizzled 16B chunks
    __shared__ float en_s[512];
    __shared__ float dist_s[256];
    __shared__ int   idx_s[256];
    __shared__ int   hist_s[512];
    __shared__ float lpart_s[4];

    const int t = threadIdx.x, wg = blockIdx.x;
    const int w = t >> 6, lane = t & 63;
    const int c = lane & 15, g = lane >> 4;
    const int b = wg >> 2;
    const int sp0 = (wg & 3) << 8;
    float* qout = out + OFF_QUANT;
    float* oh   = out + OFF_OH;
    float* loss_g = (float*)wsi;
    int*   done_g = wsi + 1;
    int*   cnt_g  = wsi + 2;
    const short* elo_t = (const short*)(wsi + W_ELO);

    if (t < 512) hist_s[t] = 0;

    // ---- stage codebook-hi -> LDS (swizzled) ----
    const float4* cb4 = (const float4*)cb;
#pragma unroll
    for (int i = 0; i < 16; ++i) {
        int e4 = i * 512 + t;                  // 8192 float4 = full codebook
        float4 v = cb4[e4];
        int k = e4 >> 4, q4 = e4 & 15;
        int base = (k << 6) + ((((q4 >> 1) ^ (k & 7)) << 3) + ((q4 & 1) << 2));
        float vv[4] = {v.x, v.y, v.z, v.w};
        short4v h4;
#pragma unroll
        for (int e = 0; e < 4; ++e) h4[e] = (short)f2bf(vv[e]);
        *(short4v*)&Ehi[base] = h4;
    }
    // ---- ||e||^2 fp32 (L2-hot) ----
    {
        const float4* r4 = cb4 + (t << 4);
        float s = 0.f;
#pragma unroll
        for (int j = 0; j < 16; ++j) {
            float4 vv = r4[j];
            s = fmaf(vv.x, vv.x, s); s = fmaf(vv.y, vv.y, s);
            s = fmaf(vv.z, vv.z, s); s = fmaf(vv.w, vv.w, s);
        }
        en_s[t] = s;
    }

    // ---- X B-frags + xnorm, registers only ----
    short8 bh[2][2], bl[2][2];
    float xnorm[2];
    const float* xb = x + (((size_t)b) << 16) + sp0 + (w << 5) + c;
#pragma unroll
    for (int xt = 0; xt < 2; ++xt) {
        float xn2 = 0.f;
#pragma unroll
        for (int ks = 0; ks < 2; ++ks) {
            short8 h8, l8;
#pragma unroll
            for (int e = 0; e < 8; ++e) {
                float xv = xb[(xt << 4) + ((size_t)((ks << 5) + (g << 3) + e) << 10)];
                unsigned short hh = f2bf(xv);
                h8[e] = (short)hh;
                l8[e] = (short)f2bf(xv - bf2f(hh));
                xn2 = fmaf(xv, xv, xn2);
            }
            bh[xt][ks] = h8; bl[xt][ks] = l8;
        }
        xn2 += __shfl_xor(xn2, 16);
        xn2 += __shfl_xor(xn2, 32);
        xnorm[xt] = xn2;
    }
    __syncthreads();

    // ---- MFMA argmin over 32 k-tiles ----
    float v1[2] = {FLT_MAX, FLT_MAX}, v2[2] = {FLT_MAX, FLT_MAX};
    int   i1[2] = {0, 0},            i2v[2] = {0, 0};
    const int sw = c & 7;
    const short* ph = &Ehi[c << 6];
    const short* pel = elo_t + (c << 6) + (g << 3);
    for (int kt = 0; kt < 32; ++kt) {
        const short* rh = ph + (kt << 10);
        short8 ah0 = *(const short8*)(rh + ((g ^ sw) << 3));
        short8 ah1 = *(const short8*)(rh + (((g + 4) ^ sw) << 3));
        short8 al0 = *(const short8*)(pel + (kt << 10));
        short8 al1 = *(const short8*)(pel + (kt << 10) + 32);
        float4 en4 = *(const float4*)&en_s[(kt << 4) + (g << 2)];
        float en_[4] = {en4.x, en4.y, en4.z, en4.w};
#pragma unroll
        for (int xt = 0; xt < 2; ++xt) {
            f32x4 acc = {0.f, 0.f, 0.f, 0.f};
            acc = __builtin_amdgcn_mfma_f32_16x16x32_bf16(ah0, bh[xt][0], acc, 0, 0, 0);
            acc = __builtin_amdgcn_mfma_f32_16x16x32_bf16(ah1, bh[xt][1], acc, 0, 0, 0);
            acc = __builtin_amdgcn_mfma_f32_16x16x32_bf16(al0, bh[xt][0], acc, 0, 0, 0);
            acc = __builtin_amdgcn_mfma_f32_16x16x32_bf16(al1, bh[xt][1], acc, 0, 0, 0);
            acc = __builtin_amdgcn_mfma_f32_16x16x32_bf16(ah0, bl[xt][0], acc, 0, 0, 0);
            acc = __builtin_amdgcn_mfma_f32_16x16x32_bf16(ah1, bl[xt][1], acc, 0, 0, 0);
#pragma unroll
            for (int r = 0; r < 4; ++r) {
                float dd = fmaf(-2.0f, acc[r], en_[r]);
                int k = (kt << 4) + (g << 2) + r;
                bool lt1 = dd < v1[xt];
                bool lt2 = dd < v2[xt];
                v2[xt] = lt1 ? v1[xt] : (lt2 ? dd : v2[xt]);
                i2v[xt] = lt1 ? i1[xt] : (lt2 ? k : i2v[xt]);
                v1[xt] = lt1 ? dd : v1[xt];
                i1[xt] = lt1 ? k : i1[xt];
            }
        }
    }

    // ---- cross-lane merge (lanes c,c+16,c+32,c+48 hold disjoint k-classes) ----
#pragma unroll
    for (int xt = 0; xt < 2; ++xt) {
        float V1 = v1[xt], V2 = v2[xt]; int I1 = i1[xt], I2 = i2v[xt];
#pragma unroll
        for (int off = 16; off <= 32; off <<= 1) {
            float o1 = __shfl_xor(V1, off); int oi1 = __shfl_xor(I1, off);
            float o2 = __shfl_xor(V2, off); int oi2 = __shfl_xor(I2, off);
            if (o1 < V1 || (o1 == V1 && oi1 < I1)) {
                V2 = V1; I2 = I1; V1 = o1; I1 = oi1;
            } else if (o1 < V2 || (o1 == V2 && oi1 < I2)) { V2 = o1; I2 = oi1; }
            if (o2 < V2 || (o2 == V2 && oi2 < I2)) { V2 = o2; I2 = oi2; }
        }
        if (g == 0) {
            int r = (w << 5) + (xt << 4) + c;
            idx_s[r]  = I1 | ((V2 - V1 < TAU) ? FLAG_BIT : 0);
            dist_s[r] = xnorm[xt] + V1;
        }
    }

    // ---- wave-local fp64 recheck of near-ties ----
    {
        int rbase = w << 5;
        int rowfull = (lane < 32) ? idx_s[rbase + lane] : 0;
        unsigned long long m = __ballot((lane < 32) && (rowfull & FLAG_BIT));
        while (m) {
            int r = __ffsll((long long)m) - 1; m &= m - 1;
            int sp = sp0 + rbase + r;
            float xd = x[(((size_t)b) << 16) + (((size_t)lane) << 10) + sp];  // lane=d
            double bestd = 1e300; int besti = 0x7fffffff;
            for (int kk = 0; kk < 8; ++kk) {
                int k = (lane << 3) + kk;
                double s = 0.0;
#pragma unroll
                for (int d4 = 0; d4 < 16; ++d4) {
                    float4 e4 = cb4[(k << 4) + d4];
                    float x0 = __shfl(xd, d4 * 4 + 0);
                    float x1 = __shfl(xd, d4 * 4 + 1);
                    float x2 = __shfl(xd, d4 * 4 + 2);
                    float x3 = __shfl(xd, d4 * 4 + 3);
                    double f0 = (double)x0 - (double)e4.x; s = fma(f0, f0, s);
                    double f1 = (double)x1 - (double)e4.y; s = fma(f1, f1, s);
                    double f2 = (double)x2 - (double)e4.z; s = fma(f2, f2, s);
                    double f3 = (double)x3 - (double)e4.w; s = fma(f3, f3, s);
                }
                if (s < bestd || (s == bestd && k < besti)) { bestd = s; besti = k; }
            }
#pragma unroll
            for (int off = 32; off; off >>= 1) {
                double od = __shfl_xor(bestd, off);
                int    oi = __shfl_xor(besti, off);
                if (od < bestd || (od == bestd && oi < besti)) { bestd = od; besti = oi; }
            }
            if (lane == 0) {
                idx_s[rbase + r]  = besti;
                dist_s[rbase + r] = (float)bestd;
            }
        }
    }
    __syncthreads();

    // ---- WG stats: strip flags, histogram, loss partial ----
    if (t < 256) {
        int k = idx_s[t] & 511;
        idx_s[t] = k;
        atomicAdd(&hist_s[k], 1);
        float lv = dist_s[t];
#pragma unroll
        for (int off = 1; off < 64; off <<= 1) lv += __shfl_xor(lv, off);
        if (lane == 0) lpart_s[w] = lv;
    }
    __syncthreads();
    // publish: one atomic per nonzero counter; loss + done from t==0
    if (t < 512 && hist_s[t]) atomicAdd(&cnt_g[t], hist_s[t]);
    if (t == 0) {
        atomicAdd(loss_g, lpart_s[0] + lpart_s[1] + lpart_s[2] + lpart_s[3]);
        __hip_atomic_fetch_add(done_g, 1, __ATOMIC_RELEASE, __HIP_MEMORY_SCOPE_AGENT);
    }

    // ---- onehot zero-fill: WG slice = [b][k=0..511][sp0..sp0+256) ----
    {
        float4 z4 = {0.f, 0.f, 0.f, 0.f};
        float2 z2 = {0.f, 0.f};
        float* base_wg = oh + (((size_t)b) << 19) + sp0;
        for (int it = 0; it < 64; ++it) {
            int k = (it << 3) + w;
            float* cbase = base_wg + (((size_t)k) << 10);
            if (lane < 63)
                *(float4*)(cbase + 2 + (lane << 2)) = z4;   // floats 2..253
            else {
                *(float2*)(cbase)       = z2;               // floats 0,1
                *(float2*)(cbase + 254) = z2;               // floats 254,255
            }
        }
    }
    __syncthreads();   // drain zeros before scatter

    // ---- scatter the 256 ones ----
    if (t < 256) {
        int k = idx_s[t];
        oh[(((size_t)b) << 19) + (((size_t)k) << 10) + sp0 + t] = 1.0f;
    }

    // ---- quant: exact fp32 gather from codebook (L2-hot) ----
    {
        int r = t & 255, half = t >> 8;
        int k = idx_s[r];
        float* qb = qout + (((size_t)b) << 16) + sp0 + r;
#pragma unroll
        for (int j = 0; j < 8; ++j) {
            float4 v = cb4[(k << 4) + (half << 3) + j];
            int d0 = (half << 5) + (j << 2);
            qb[((size_t)(d0 + 0)) << 10] = v.x;
            qb[((size_t)(d0 + 1)) << 10] = v.y;
            qb[((size_t)(d0 + 2)) << 10] = v.z;
            qb[((size_t)(d0 + 3)) << 10] = v.w;
        }
    }

    // ---- WG0: wait for all, then perplexity + loss ----
    if (wg == 0) {
        if (t == 0) {
            while (__hip_atomic_load(done_g, __ATOMIC_ACQUIRE,
                                     __HIP_MEMORY_SCOPE_AGENT) != 512)
                __builtin_amdgcn_s_sleep(2);
        }
        __syncthreads();
        float plog = 0.f;
        {
            int s = __hip_atomic_load(&cnt_g[t], __ATOMIC_RELAXED,
                                      __HIP_MEMORY_SCOPE_AGENT);
            float p = (float)s * (1.f / (float)NTOT);
            plog = p * logf(p + 1e-10f);
        }
#pragma unroll
        for (int off = 1; off < 64; off <<= 1) plog += __shfl_xor(plog, off);
        if (lane == 0) en_s[w] = plog;   // en_s dead; reuse
        __syncthreads();
        if (t == 0) {
            float ps = 0.f;
            for (int i = 0; i < 8; ++i) ps += en_s[i];
            out[OFF_PERP] = expf(-ps);
            float ls = *((volatile float*)loss_g);
            out[OFF_LOSS] = 0.25f * ls / ((float)NTOT * 64.0f);
        }
    }
}

extern "C" void kernel_launch(void* const* d_in, const int* in_sizes, int n_in,
                              void* d_out, int out_size, void* d_ws, size_t ws_size,
                              hipStream_t stream) {
    const float* x  = (const float*)d_in[0];
    const float* cb = (const float*)d_in[1];
    vq_prep<<<2,   512, 0, stream>>>(cb, (int*)d_ws);
    vq_main<<<512, 512, 0, stream>>>(x, cb, (int*)d_ws, (float*)d_out);
}